// Round 1
// baseline (144.451 us; speedup 1.0000x reference)
//
#include <hip/hip_runtime.h>
#include <stdint.h>

#define WW   361     // W*W spatial positions
#define CCH  64      // channels (K)
#define MH   192     // support rows per block (i-half)
#define NPAD 384     // query rows padded to 24 tiles of 16
#define NBS  600     // B*S

typedef __attribute__((ext_vector_type(8))) short short8;
typedef __attribute__((ext_vector_type(4))) float f32x4;

__device__ __forceinline__ unsigned short f2bf(float f) {
  union { float f; unsigned int u; } c; c.f = f;
  unsigned int x = c.u;
  unsigned int r = (x + 0x7fffu + ((x >> 16) & 1u)) >> 16;  // RNE
  return (unsigned short)r;
}

// LDS layout: row-major [row][k], pitch 64 bf16 (128B), with 16B-chunk XOR
// swizzle: element (m,k) lives at m*64 + ((k/8)^(m&7))*8 + (k&7).
// - staging b128 stores (consecutive m, fixed chunk) -> bank-uniform
// - fragment b128 reads (16 consecutive m, fixed logical chunk) -> bank-uniform

__global__ __launch_bounds__(384) void cossim_max_kernel(
    const float* __restrict__ support, const float* __restrict__ query,
    float* __restrict__ out)
{
  __shared__ __align__(16) unsigned short S_sh[MH * CCH];
  __shared__ __align__(16) unsigned short Q_sh[NPAD * CCH];
  __shared__ float inv_s[MH];
  __shared__ float inv_q[NPAD];

  const int tid  = threadIdx.x;
  const int bs   = blockIdx.x >> 1;
  const int half = blockIdx.x & 1;
  const int mBase = half * MH;

  const float* sg = support + (size_t)bs * (WW * CCH);
  const float* qg = query   + (size_t)bs * (WW * CCH);

  if (tid < MH) inv_s[tid] = 0.f;
  __syncthreads();

  // ---- Query staging: thread owns row m = tid (global [k][m] -> LDS [m][k]) ----
  {
    const int m = tid;
    const int sw = m & 7;
    if (m < WW) {
      const float* gp = qg + m;
      float ssq = 0.f;
      #pragma unroll
      for (int c = 0; c < 8; ++c) {
        float v[8];
        #pragma unroll
        for (int j = 0; j < 8; ++j) v[j] = gp[(c * 8 + j) * WW]; // coalesced across lanes
        unsigned int u[4];
        #pragma unroll
        for (int jj = 0; jj < 4; ++jj) {
          ssq += v[2*jj]*v[2*jj] + v[2*jj+1]*v[2*jj+1];
          u[jj] = (unsigned int)f2bf(v[2*jj]) | ((unsigned int)f2bf(v[2*jj+1]) << 16);
        }
        *(uint4*)&Q_sh[m * CCH + ((c ^ sw) * 8)] = make_uint4(u[0], u[1], u[2], u[3]);
      }
      inv_q[m] = rsqrtf(ssq);
    } else {
      // zero-fill pad rows so pad-p accumulators are exactly 0 (bias trick)
      #pragma unroll
      for (int c = 0; c < 8; ++c)
        *(uint4*)&Q_sh[m * CCH + ((c ^ sw) * 8)] = make_uint4(0u, 0u, 0u, 0u);
      inv_q[m] = 0.f;
    }
  }

  // ---- Support staging: two threads per row (chunks 0-3 / 4-7) ----
  {
    const int mL = (tid < MH) ? tid : (tid - MH);
    const int cB = (tid < MH) ? 0 : 4;
    const int mG = mBase + mL;
    const int sw = mL & 7;
    if (mG < WW) {
      const float* gp = sg + mG;
      float ssq = 0.f;
      #pragma unroll
      for (int c0 = 0; c0 < 4; ++c0) {
        const int c = cB + c0;
        float v[8];
        #pragma unroll
        for (int j = 0; j < 8; ++j) v[j] = gp[(c * 8 + j) * WW];
        unsigned int u[4];
        #pragma unroll
        for (int jj = 0; jj < 4; ++jj) {
          ssq += v[2*jj]*v[2*jj] + v[2*jj+1]*v[2*jj+1];
          u[jj] = (unsigned int)f2bf(v[2*jj]) | ((unsigned int)f2bf(v[2*jj+1]) << 16);
        }
        *(uint4*)&S_sh[mL * CCH + ((c ^ sw) * 8)] = make_uint4(u[0], u[1], u[2], u[3]);
      }
      atomicAdd(&inv_s[mL], ssq);
    }
  }
  __syncthreads();
  if (tid < MH) inv_s[tid] = rsqrtf(inv_s[tid]);
  __syncthreads();

  // ---- Compute: wave w handles i-tiles {2w, 2w+1}; iterates all 24 p-tiles ----
  const int lane = tid & 63;
  const int wv   = tid >> 6;     // 0..5
  const int l15  = lane & 15;
  const int quad = lane >> 4;    // 0..3

  // A fragments held in registers for the whole p-loop.
  // A[m = l15][k = quad*8+j], k-step s covers k in [s*32, s*32+32)
  short8 af[2][2];
  #pragma unroll
  for (int t = 0; t < 2; ++t) {
    const int m = 32 * wv + 16 * t + l15;
    #pragma unroll
    for (int s = 0; s < 2; ++s) {
      const int c = 4 * s + quad;
      af[t][s] = *(const short8*)&S_sh[m * CCH + ((c ^ (m & 7)) * 8)];
    }
  }

  f32x4 mx0 = {-3e38f, -3e38f, -3e38f, -3e38f};
  f32x4 mx1 = {-3e38f, -3e38f, -3e38f, -3e38f};

  for (int pt = 0; pt < NPAD / 16; ++pt) {
    const int n  = 16 * pt + l15;
    const int sw = n & 7;          // == l15&7, constant across pt
    short8 b0 = *(const short8*)&Q_sh[n * CCH + (((0 + quad) ^ sw) * 8)];
    short8 b1 = *(const short8*)&Q_sh[n * CCH + (((4 + quad) ^ sw) * 8)];
    f32x4 acc0 = {0.f, 0.f, 0.f, 0.f};
    f32x4 acc1 = {0.f, 0.f, 0.f, 0.f};
    acc0 = __builtin_amdgcn_mfma_f32_16x16x32_bf16(af[0][0], b0, acc0, 0, 0, 0);
    acc0 = __builtin_amdgcn_mfma_f32_16x16x32_bf16(af[0][1], b1, acc0, 0, 0, 0);
    acc1 = __builtin_amdgcn_mfma_f32_16x16x32_bf16(af[1][0], b0, acc1, 0, 0, 0);
    acc1 = __builtin_amdgcn_mfma_f32_16x16x32_bf16(af[1][1], b1, acc1, 0, 0, 0);
    const float qs   = inv_q[n];
    const float bias = (n < WW) ? 0.f : -1e30f;  // pad p: acc==0 -> -1e30, never wins
    #pragma unroll
    for (int r = 0; r < 4; ++r) {
      mx0[r] = fmaxf(mx0[r], acc0[r] * qs + bias);
      mx1[r] = fmaxf(mx1[r], acc1[r] * qs + bias);
    }
  }

  // max over columns: butterfly across the 16 lanes of each quad group
  #pragma unroll
  for (int d = 1; d < 16; d <<= 1) {
    #pragma unroll
    for (int r = 0; r < 4; ++r) {
      mx0[r] = fmaxf(mx0[r], __shfl_xor(mx0[r], d));
      mx1[r] = fmaxf(mx1[r], __shfl_xor(mx1[r], d));
    }
  }

  // C/D layout: row = quad*4 + reg; one writer lane per quad group
  if (l15 == 0) {
    #pragma unroll
    for (int t = 0; t < 2; ++t) {
      #pragma unroll
      for (int r = 0; r < 4; ++r) {
        const int mL = 32 * wv + 16 * t + 4 * quad + r;
        const int iG = mBase + mL;
        if (iG < WW) {
          const float val = (t == 0 ? mx0[r] : mx1[r]) * inv_s[mL];
          out[(size_t)bs * WW + iG] = val;
        }
      }
    }
  }
}

extern "C" void kernel_launch(void* const* d_in, const int* in_sizes, int n_in,
                              void* d_out, int out_size, void* d_ws, size_t ws_size,
                              hipStream_t stream) {
  const float* support = (const float*)d_in[0];
  const float* query   = (const float*)d_in[1];
  float* out = (float*)d_out;
  dim3 grid(NBS * 2), block(384);
  hipLaunchKernelGGL(cossim_max_kernel, grid, block, 0, stream,
                     support, query, out);
}

// Round 2
// 140.862 us; speedup vs baseline: 1.0255x; 1.0255x over previous
//
#include <hip/hip_runtime.h>
#include <hip/hip_bf16.h>
#include <stdint.h>

#define WW   361     // W*W spatial positions
#define CCH  64      // channels (K)
#define MH   128     // support rows per block (i-third)
#define NP   368     // query rows padded to 23 tiles of 16
#define NBS  600     // B*S

typedef __attribute__((ext_vector_type(8))) short short8;
typedef __attribute__((ext_vector_type(4))) float f32x4;

// LDS layout: row-major [row][k], pitch 64 bf16 (128B), 16B-chunk XOR swizzle:
// element (m,k) at m*64 + ((k/8 ^ (m&7))*8) + (k&7).  Proven conflict-free in R1
// (SQ_LDS_BANK_CONFLICT == 0) for both b128 stores and b128 fragment reads.

// Stage one row: 64 floats strided by WW from gp, bf16-pack into dst (= sh + m*CCH),
// return rsqrt(sum of squares). 32 loads in flight per batch for MLP.
__device__ __forceinline__ float stage_row(const float* __restrict__ gp,
                                           unsigned short* __restrict__ dst, int sw) {
  float a0 = 0.f, a1 = 0.f, a2 = 0.f, a3 = 0.f;
  #pragma unroll
  for (int h = 0; h < 2; ++h) {
    float v[32];
    #pragma unroll
    for (int j = 0; j < 32; ++j) v[j] = gp[(h * 32 + j) * WW];  // coalesced across lanes
    #pragma unroll
    for (int j = 0; j < 32; j += 4) {
      a0 += v[j] * v[j];     a1 += v[j+1] * v[j+1];
      a2 += v[j+2] * v[j+2]; a3 += v[j+3] * v[j+3];
    }
    #pragma unroll
    for (int c0 = 0; c0 < 4; ++c0) {
      const int c = h * 4 + c0;
      unsigned int u[4];
      #pragma unroll
      for (int jj = 0; jj < 4; ++jj) {
        __hip_bfloat162 b2 =
            __float22bfloat162_rn(make_float2(v[c0 * 8 + 2 * jj], v[c0 * 8 + 2 * jj + 1]));
        u[jj] = *(unsigned int*)&b2;
      }
      *(uint4*)&dst[(c ^ sw) * 8] = make_uint4(u[0], u[1], u[2], u[3]);
    }
  }
  return rsqrtf(a0 + a1 + a2 + a3);
}

__device__ __forceinline__ void zero_row(unsigned short* __restrict__ dst) {
  #pragma unroll
  for (int c = 0; c < 8; ++c)
    *(uint4*)&dst[c * 8] = make_uint4(0u, 0u, 0u, 0u);  // swizzle irrelevant for zeros
}

__global__ __launch_bounds__(512, 4) void cossim_max_kernel(
    const float* __restrict__ support, const float* __restrict__ query,
    float* __restrict__ out)
{
  __shared__ __align__(16) unsigned short S_sh[MH * CCH];  // 16384 B
  __shared__ __align__(16) unsigned short Q_sh[NP * CCH];  // 47104 B
  __shared__ float inv_s[MH];                              //   512 B
  __shared__ float inv_q[NP];                              //  1472 B  -> 65472 B total

  const int tid   = threadIdx.x;
  const int bs    = blockIdx.x / 3;
  const int third = blockIdx.x % 3;
  const int mBase = third * MH;

  const float* sg = support + (size_t)bs * (WW * CCH);
  const float* qg = query   + (size_t)bs * (WW * CCH);

  // ---- Staging: one thread owns one full row; no atomics, single barrier ----
  if (tid < NP) {
    const int m = tid;
    if (m < WW) {
      inv_q[m] = stage_row(qg + m, &Q_sh[m * CCH], m & 7);
    } else {
      zero_row(&Q_sh[m * CCH]);   // pad rows: acc==0 -> bias trick in epilogue
      inv_q[m] = 0.f;
    }
  } else if (tid < NP + MH) {
    const int mL = tid - NP;
    const int mG = mBase + mL;
    if (mG < WW) {
      inv_s[mL] = stage_row(sg + mG, &S_sh[mL * CCH], mL & 7);
    } else {
      zero_row(&S_sh[mL * CCH]);  // keep MFMA inputs NaN-free
      inv_s[mL] = 0.f;
    }
  }
  __syncthreads();

  // ---- Compute: wave w owns i-tile w (rows 16w..16w+15), loops 23 p-tiles ----
  const int lane = tid & 63;
  const int wv   = tid >> 6;     // 0..7
  const int l15  = lane & 15;
  const int quad = lane >> 4;    // 0..3

  // A fragment: A[m = l15][k = quad*8+j]; k-half s covers k in [s*32, s*32+32)
  short8 af[2];
  {
    const int m = 16 * wv + l15;
    #pragma unroll
    for (int s = 0; s < 2; ++s) {
      const int c = 4 * s + quad;
      af[s] = *(const short8*)&S_sh[m * CCH + ((c ^ (m & 7)) * 8)];
    }
  }

  f32x4 mx = {-3e38f, -3e38f, -3e38f, -3e38f};

  for (int pt = 0; pt < NP / 16; ++pt) {
    const int n  = 16 * pt + l15;
    const int sw = l15 & 7;                 // == n&7 (16pt ≡ 0 mod 8)
    short8 b0 = *(const short8*)&Q_sh[n * CCH + (((0 + quad) ^ sw) * 8)];
    short8 b1 = *(const short8*)&Q_sh[n * CCH + (((4 + quad) ^ sw) * 8)];
    f32x4 acc = {0.f, 0.f, 0.f, 0.f};
    acc = __builtin_amdgcn_mfma_f32_16x16x32_bf16(af[0], b0, acc, 0, 0, 0);
    acc = __builtin_amdgcn_mfma_f32_16x16x32_bf16(af[1], b1, acc, 0, 0, 0);
    const float qs   = inv_q[n];
    const float bias = (n < WW) ? 0.f : -1e30f;  // pad p: acc==0 -> never wins
    #pragma unroll
    for (int r = 0; r < 4; ++r) mx[r] = fmaxf(mx[r], acc[r] * qs + bias);
  }

  // max over columns (C layout: col = lane&15): butterfly within each 16-lane group
  #pragma unroll
  for (int d = 1; d < 16; d <<= 1) {
    #pragma unroll
    for (int r = 0; r < 4; ++r) mx[r] = fmaxf(mx[r], __shfl_xor(mx[r], d));
  }

  // C/D layout: row = quad*4 + reg; one writer lane per 16-lane group
  if (l15 == 0) {
    #pragma unroll
    for (int r = 0; r < 4; ++r) {
      const int mL = 16 * wv + 4 * quad + r;
      const int iG = mBase + mL;
      if (iG < WW) out[(size_t)bs * WW + iG] = mx[r] * inv_s[mL];
    }
  }
}

extern "C" void kernel_launch(void* const* d_in, const int* in_sizes, int n_in,
                              void* d_out, int out_size, void* d_ws, size_t ws_size,
                              hipStream_t stream) {
  const float* support = (const float*)d_in[0];
  const float* query   = (const float*)d_in[1];
  float* out = (float*)d_out;
  dim3 grid(NBS * 3), block(512);
  hipLaunchKernelGGL(cossim_max_kernel, grid, block, 0, stream,
                     support, query, out);
}